// Round 10
// baseline (384.714 us; speedup 1.0000x reference)
//
#include <hip/hip_runtime.h>
#include <hip/hip_cooperative_groups.h>
#include <math.h>

namespace cg = cooperative_groups;

// ============================================================================
// Mathematical collapse of the reference:
//   h = broadcast(z) over N_NODES  =>  all nodes identical within a batch.
//   Attention: all scores equal => softmax uniform => o = mean_k(v) = v.
//   Edge logits are ONE 2-vector c[b] per batch; straight-through gumbel
//   forward-evals to y_hard; tau>0 argmax-invariant.
//   => e[b,p] = (c0 + g0(u0) >= c1 + g1(u1)),  g(u)=-log(-log(u+1e-10)+1e-10)
//   => adj[b,i,j] symmetric, 0 diagonal.
//
// R9 lesson: __builtin_nontemporal_* requires Clang vector types, NOT HIP's
//   float2/float4 classes => use ext_vector_type typedefs f32x2/f32x4.
// R7 lessons (rocprof):
//   - adj_tile: 48us @ 29% HBM peak, VGPR_Count=16 => register-minimized,
//     ~2-4 loads in flight => latency-limited. FIX: hoist all 16 u-loads
//     into registers up front (off-diag fast path), nontemporal ld/st.
//   - head stages ~4.8us x 8 ~= 38us, mostly launch/drain floor. FIX: one
//     COOPERATIVE kernel, 64 blocks x 256 thr, grid.sync() between stages,
//     __threadfence() around each sync for cross-XCD visibility. Runtime
//     fallback to the proven 8-launch path if coop launch is rejected.
//   - logf stays PRECISE libm (absmax 0.0; fast-log ulp diffs risk flips).
// R6 lesson: big scratch must NOT live in d_ws (OOB corrupted durable
//   buffers). G/H/T live in the TAIL of d_out, fully consumed before
//   adj_tile_kernel overwrites all of d_out. c (32 doubles) stays in d_ws.
// ============================================================================

#define NN    1024
#define HD    256
#define DIN0  71
#define NPAIR 523776   // 1024*1023/2
#define TILE  64
#define NT    16       // NN / TILE

typedef float f32x2 __attribute__((ext_vector_type(2)));
typedef float f32x4 __attribute__((ext_vector_type(4)));

// ---------------------------------------------------------------------------
// shared helpers (256-thread blocks = 4 waves)
// ---------------------------------------------------------------------------
__device__ __forceinline__ double bred(double v, double* red4) {
  #pragma unroll
  for (int m = 32; m > 0; m >>= 1) v += __shfl_xor(v, m, 64);
  const int wid = threadIdx.x >> 6;
  __syncthreads();
  if ((threadIdx.x & 63) == 0) red4[wid] = v;
  __syncthreads();
  return (red4[0] + red4[1]) + (red4[2] + red4[3]);
}

__device__ __forceinline__ double quad_sum(double v) {
  v += __shfl_xor(v, 1, 64);
  v += __shfl_xor(v, 2, 64);
  return v;
}

// quarter-dot over 256 LDS doubles with f32 weight row (float4 loads)
__device__ __forceinline__ double dotq256(const double* s,
                                          const float* __restrict__ W,
                                          int row, int p) {
  const float4* w4 = reinterpret_cast<const float4*>(W + (size_t)row * 256);
  double a0 = 0.0, a1 = 0.0, a2 = 0.0, a3 = 0.0;
  #pragma unroll
  for (int k = 0; k < 16; ++k) {
    const int f = p + 4 * k;
    float4 w = w4[f];
    const double* sp = s + 4 * f;
    a0 += sp[0] * (double)w.x;
    a1 += sp[1] * (double)w.y;
    a2 += sp[2] * (double)w.z;
    a3 += sp[3] * (double)w.w;
  }
  return (a0 + a1) + (a2 + a3);
}

// quarter-dot over DIN0=71 LDS doubles (scalar, stride 4)
__device__ __forceinline__ double dotq71(const double* s,
                                         const float* __restrict__ W,
                                         int row, int p) {
  const float* wr = W + (size_t)row * DIN0;
  double a = 0.0;
  #pragma unroll
  for (int i = p; i < DIN0; i += 4) a += s[i] * (double)wr[i];
  return a;
}

__device__ __forceinline__ double gelu_exact(double x) {
  return 0.5 * x * (1.0 + erf(x * 0.70710678118654752440));
}

// compute ln0(z) for batch b into LDS h0[71] (threads 0..70 write)
__device__ __forceinline__ void ln0_into(const float* __restrict__ x,
                                         const float* __restrict__ stats,
                                         const float* __restrict__ g,
                                         const float* __restrict__ bb,
                                         int b, double* h0, double* red4) {
  const int tid = threadIdx.x;
  double z = 0.0;
  if (tid < DIN0)
    z = (tid < 64) ? (double)x[b * 64 + tid] : (double)stats[b * 7 + tid - 64];
  const double m = bred((tid < DIN0) ? z : 0.0, red4) / (double)DIN0;
  const double d = (tid < DIN0) ? (z - m) : 0.0;
  const double var = bred(d * d, red4) / (double)DIN0;
  const double inv = 1.0 / sqrt(var + (double)1e-5f);
  if (tid < DIN0) h0[tid] = d * inv * (double)g[tid] + (double)bb[tid];
  __syncthreads();
}

// LN over a 256-wide global vector S[b] -> LDS dst (all 256 threads)
__device__ __forceinline__ void ln256_into(const double* __restrict__ S, int b,
                                           const float* __restrict__ lg,
                                           const float* __restrict__ lb,
                                           double* dst, double* red4) {
  const int tid = threadIdx.x;
  const double s = S[b * HD + tid];
  const double m = bred(s, red4) / (double)HD;
  const double d = s - m;
  const double var = bred(d * d, red4) / (double)HD;
  const double inv = 1.0 / sqrt(var + (double)1e-5f);
  dst[tid] = d * inv * (double)lg[tid] + (double)lb[tid];
  __syncthreads();
}

// ---------------------------------------------------------------------------
// head_coop: ONE cooperative kernel, 64 blocks (b*4+rg) x 256 threads.
// ---------------------------------------------------------------------------
__global__ __launch_bounds__(256)
void head_coop(const float* __restrict__ x, const float* __restrict__ stats,
               const float* __restrict__ ln0_g, const float* __restrict__ ln0_b,
               const float* __restrict__ rb1_ln_g, const float* __restrict__ rb1_ln_b,
               const float* __restrict__ rb1_w1, const float* __restrict__ rb1_b1,
               const float* __restrict__ rb1_w2, const float* __restrict__ rb1_b2,
               const float* __restrict__ rb1_wp, const float* __restrict__ rb1_bp,
               const float* __restrict__ rb2_ln_g, const float* __restrict__ rb2_ln_b,
               const float* __restrict__ rb2_w1, const float* __restrict__ rb2_b1,
               const float* __restrict__ rb2_w2, const float* __restrict__ rb2_b2,
               const float* __restrict__ att_ln_g, const float* __restrict__ att_ln_b,
               const float* __restrict__ att_win_v, const float* __restrict__ att_bin_v,
               const float* __restrict__ att_wout, const float* __restrict__ att_bout,
               const float* __restrict__ out_w, const float* __restrict__ out_b,
               const float* __restrict__ fin_w, const float* __restrict__ fin_b,
               double* __restrict__ G, double* __restrict__ H,
               double* __restrict__ T, double* __restrict__ c_out) {
  cg::grid_group grid = cg::this_grid();
  __shared__ double sv[HD], h0[DIN0], red[4];
  const int tid = threadIdx.x;
  const int b = blockIdx.x >> 2, rg = blockIdx.x & 3;
  const int row = rg * 64 + (tid >> 2), p = tid & 3;

#define GSYNC() do { __threadfence(); grid.sync(); __threadfence(); } while (0)

  // S1: G = gelu(W1 @ rb1_ln(ln0(z)) + b1);  h0 = ln0(z) persists in LDS
  ln0_into(x, stats, ln0_g, ln0_b, b, h0, red);
  {
    double v = (tid < DIN0) ? h0[tid] : 0.0;
    const double m = bred(v, red) / (double)DIN0;
    const double d = (tid < DIN0) ? (h0[tid] - m) : 0.0;
    const double var = bred(d * d, red) / (double)DIN0;
    const double inv = 1.0 / sqrt(var + (double)1e-5f);
    if (tid < DIN0) sv[tid] = d * inv * (double)rb1_ln_g[tid] + (double)rb1_ln_b[tid];
    __syncthreads();
  }
  {
    const double d = quad_sum(dotq71(sv, rb1_w1, row, p));
    if (p == 0) G[b * HD + row] = gelu_exact(d + (double)rb1_b1[row]);
  }
  GSYNC();

  // S2: H = (W2 @ G + b2) + (Wp @ h0 + bp)
  sv[tid] = G[b * HD + tid];
  __syncthreads();
  {
    const double d2 = quad_sum(dotq256(sv, rb1_w2, row, p));
    const double dp = quad_sum(dotq71(h0, rb1_wp, row, p));
    if (p == 0)
      H[b * HD + row] = (d2 + (double)rb1_b2[row]) + (dp + (double)rb1_bp[row]);
  }
  GSYNC();

  // S3: G = gelu(rb2_w1 @ LN(H) + b1)
  ln256_into(H, b, rb2_ln_g, rb2_ln_b, sv, red);
  {
    const double d = quad_sum(dotq256(sv, rb2_w1, row, p));
    if (p == 0) G[b * HD + row] = gelu_exact(d + (double)rb2_b1[row]);
  }
  GSYNC();

  // S4: H += rb2_w2 @ G + b2
  sv[tid] = G[b * HD + tid];
  __syncthreads();
  {
    const double d = quad_sum(dotq256(sv, rb2_w2, row, p));
    if (p == 0) H[b * HD + row] += d + (double)rb2_b2[row];
  }
  GSYNC();

  // S5: G = att_win_v @ LN(H) + att_bin_v   (attention collapses to o = v)
  ln256_into(H, b, att_ln_g, att_ln_b, sv, red);
  {
    const double d = quad_sum(dotq256(sv, att_win_v, row, p));
    if (p == 0) G[b * HD + row] = d + (double)att_bin_v[row];
  }
  GSYNC();

  // S6: T = att_wout @ G + att_bout
  sv[tid] = G[b * HD + tid];
  __syncthreads();
  {
    const double d = quad_sum(dotq256(sv, att_wout, row, p));
    if (p == 0) T[b * HD + row] = d + (double)att_bout[row];
  }
  GSYNC();

  // S7: G = out_w @ T + out_b    (h_final)
  sv[tid] = T[b * HD + tid];
  __syncthreads();
  {
    const double d = quad_sum(dotq256(sv, out_w, row, p));
    if (p == 0) G[b * HD + row] = d + (double)out_b[row];
  }
  GSYNC();

  // S8: c[b] (rg==0 blocks only; block-uniform branch)
  if (rg == 0) {
    const double hj = G[b * HD + tid];
    const double v0 = hj * (double)fin_w[tid]          + hj * (double)fin_w[HD + tid];
    const double v1 = hj * (double)fin_w[2 * HD + tid] + hj * (double)fin_w[3 * HD + tid];
    const double c0 = bred(v0, red) + (double)fin_b[0];
    const double c1 = bred(v1, red) + (double)fin_b[1];
    if (tid == 0) {
      c_out[2 * b + 0] = c0;
      c_out[2 * b + 1] = c1;
    }
  }
#undef GSYNC
}

// ---------------------------------------------------------------------------
// Fallback stage kernels (R7-proven path). Identical math to head_coop.
// ---------------------------------------------------------------------------
__global__ __launch_bounds__(256)
void k1_ln_w1(const float* __restrict__ x, const float* __restrict__ stats,
              const float* __restrict__ ln0_g, const float* __restrict__ ln0_b,
              const float* __restrict__ l1g, const float* __restrict__ l1b,
              const float* __restrict__ W1, const float* __restrict__ b1,
              double* __restrict__ G) {
  __shared__ double t[DIN0], red[4];
  const int b = blockIdx.x >> 2, rg = blockIdx.x & 3;
  const int tid = threadIdx.x;
  ln0_into(x, stats, ln0_g, ln0_b, b, t, red);
  {
    double v = (tid < DIN0) ? t[tid] : 0.0;
    const double m = bred(v, red) / (double)DIN0;
    const double d = (tid < DIN0) ? (t[tid] - m) : 0.0;
    const double var = bred(d * d, red) / (double)DIN0;
    const double inv = 1.0 / sqrt(var + (double)1e-5f);
    __syncthreads();
    if (tid < DIN0) t[tid] = d * inv * (double)l1g[tid] + (double)l1b[tid];
    __syncthreads();
  }
  const int row = rg * 64 + (tid >> 2), p = tid & 3;
  const double d = quad_sum(dotq71(t, W1, row, p));
  if (p == 0) G[b * HD + row] = gelu_exact(d + (double)b1[row]);
}

__global__ __launch_bounds__(256)
void k2_w2_wp(const float* __restrict__ x, const float* __restrict__ stats,
              const float* __restrict__ ln0_g, const float* __restrict__ ln0_b,
              const float* __restrict__ W2, const float* __restrict__ b2,
              const float* __restrict__ Wp, const float* __restrict__ bp,
              const double* __restrict__ G, double* __restrict__ H) {
  __shared__ double h0[DIN0], gs[HD], red[4];
  const int b = blockIdx.x >> 2, rg = blockIdx.x & 3;
  const int tid = threadIdx.x;
  gs[tid] = G[b * HD + tid];
  ln0_into(x, stats, ln0_g, ln0_b, b, h0, red);
  const int row = rg * 64 + (tid >> 2), p = tid & 3;
  const double d2 = quad_sum(dotq256(gs, W2, row, p));
  const double dp = quad_sum(dotq71(h0, Wp, row, p));
  if (p == 0)
    H[b * HD + row] = (d2 + (double)b2[row]) + (dp + (double)bp[row]);
}

__global__ __launch_bounds__(256)
void k3_ln_mv(const double* __restrict__ S,
              const float* __restrict__ lg, const float* __restrict__ lb,
              const float* __restrict__ W, const float* __restrict__ bb,
              double* __restrict__ D, int gelu_flag) {
  __shared__ double t[HD], red[4];
  const int b = blockIdx.x >> 2, rg = blockIdx.x & 3;
  ln256_into(S, b, lg, lb, t, red);
  const int row = rg * 64 + (threadIdx.x >> 2), p = threadIdx.x & 3;
  const double dd = quad_sum(dotq256(t, W, row, p));
  if (p == 0) {
    const double v = dd + (double)bb[row];
    D[b * HD + row] = gelu_flag ? gelu_exact(v) : v;
  }
}

__global__ __launch_bounds__(256)
void k4_mv_res(const double* __restrict__ G, const float* __restrict__ W,
               const float* __restrict__ bb, double* __restrict__ H) {
  __shared__ double gs[HD];
  const int b = blockIdx.x >> 2, rg = blockIdx.x & 3;
  const int tid = threadIdx.x;
  gs[tid] = G[b * HD + tid];
  __syncthreads();
  const int row = rg * 64 + (tid >> 2), p = tid & 3;
  const double d = quad_sum(dotq256(gs, W, row, p));
  if (p == 0) H[b * HD + row] += d + (double)bb[row];
}

__global__ __launch_bounds__(256)
void k5_mv(const double* __restrict__ S, const float* __restrict__ W,
           const float* __restrict__ bb, double* __restrict__ D) {
  __shared__ double ss[HD];
  const int b = blockIdx.x >> 2, rg = blockIdx.x & 3;
  const int tid = threadIdx.x;
  ss[tid] = S[b * HD + tid];
  __syncthreads();
  const int row = rg * 64 + (tid >> 2), p = tid & 3;
  const double d = quad_sum(dotq256(ss, W, row, p));
  if (p == 0) D[b * HD + row] = d + (double)bb[row];
}

__global__ __launch_bounds__(256)
void k6_fin(const double* __restrict__ Hf, const float* __restrict__ fin_w,
            const float* __restrict__ fin_b, double* __restrict__ c_out) {
  __shared__ double red[4];
  const int b = blockIdx.x;
  const int tid = threadIdx.x;
  const double hj = Hf[b * HD + tid];
  const double v0 = hj * (double)fin_w[tid]          + hj * (double)fin_w[HD + tid];
  const double v1 = hj * (double)fin_w[2 * HD + tid] + hj * (double)fin_w[3 * HD + tid];
  const double c0 = bred(v0, red) + (double)fin_b[0];
  const double c1 = bred(v1, red) + (double)fin_b[1];
  if (tid == 0) {
    c_out[2 * b + 0] = c0;
    c_out[2 * b + 1] = c1;
  }
}

// ---------------------------------------------------------------------------
// adj tile-pair kernel v2 — register-hoisted nontemporal loads (f32x2/f32x4
// ext-vector types: __builtin_nontemporal_* rejects HIP float2/float4).
// grid = (136 tile-pairs, 16 batches), 256 threads.
// ---------------------------------------------------------------------------
__global__ __launch_bounds__(256)
void adj_tile_kernel(const float* __restrict__ u, const double* __restrict__ c,
                     float* __restrict__ out) {
  __shared__ float tile[TILE][TILE + 1];   // pad 65 -> <=2-way conflicts (free)
  const int b = blockIdx.y;
  int k = blockIdx.x;                       // 0..135 -> (ti, tj), ti <= tj
  int ti = 0;
  while (k >= NT - ti) { k -= NT - ti; ++ti; }
  const int tj = ti + k;

  const int t        = threadIdx.x;
  const int lane_col = (t & 15) << 2;       // 0..60 step 4
  const int row_base = t >> 4;              // 0..15
  const double c0 = c[2 * b + 0];
  const double c1 = c[2 * b + 1];
  const float* ub = u + (size_t)b * (2u * NPAIR);
  float* ob = out + ((size_t)b << 20);

  if (ti != tj) {
    // ---- off-diagonal fast path: j > i always ----
    int pb[4];
    #pragma unroll
    for (int s = 0; s < 4; ++s) {
      const int i = ti * TILE + s * 16 + row_base;
      pb[s] = i * (2 * NN - 1 - i) / 2 - i - 1 + tj * TILE + lane_col;
    }
    // load phase: 16 independent f32x2 loads -> registers
    f32x2 r[16];
    #pragma unroll
    for (int s = 0; s < 4; ++s)
      #pragma unroll
      for (int q = 0; q < 4; ++q)
        r[s * 4 + q] = __builtin_nontemporal_load(
            reinterpret_cast<const f32x2*>(ub + 2 * (pb[s] + q)));
    // compute + store phase
    #pragma unroll
    for (int s = 0; s < 4; ++s) {
      const int il = s * 16 + row_base;
      f32x4 ev4;
      #pragma unroll
      for (int q = 0; q < 4; ++q) {
        const f32x2 uu = r[s * 4 + q];
        const float g0 = -logf(-logf(uu.x + 1e-10f) + 1e-10f);
        const float g1 = -logf(-logf(uu.y + 1e-10f) + 1e-10f);
        const float e = ((c0 + (double)g0) >= (c1 + (double)g1)) ? 1.0f : 0.0f;
        ev4[q] = e;
        tile[il][lane_col + q] = e;
      }
      const int i = ti * TILE + il;
      __builtin_nontemporal_store(ev4,
          reinterpret_cast<f32x4*>(ob + (size_t)i * NN + tj * TILE + lane_col));
    }
    __syncthreads();
    // mirrored lower tile via LDS transpose (pad -> <=2-way, free)
    #pragma unroll
    for (int s = 0; s < 4; ++s) {
      const int rl = s * 16 + row_base;
      f32x4 v;
      v[0] = tile[lane_col + 0][rl];
      v[1] = tile[lane_col + 1][rl];
      v[2] = tile[lane_col + 2][rl];
      v[3] = tile[lane_col + 3][rl];
      __builtin_nontemporal_store(v,
          reinterpret_cast<f32x4*>(ob + (size_t)(tj * TILE + rl) * NN
                                      + ti * TILE + lane_col));
    }
  } else {
    // ---- diagonal tile: masked path (R4-proven) ----
    #pragma unroll
    for (int s = 0; s < 4; ++s) {
      const int il = s * 16 + row_base;
      const int i  = ti * TILE + il;
      const int rb = i * (2 * NN - 1 - i) / 2 - i - 1;
      #pragma unroll
      for (int q = 0; q < 4; ++q) {
        const int jl = lane_col + q;
        const int j  = tj * TILE + jl;
        float e = 0.0f;
        if (j > i) {
          const int p2 = rb + j;
          const float2 uu = *reinterpret_cast<const float2*>(ub + 2 * p2);
          const float g0 = -logf(-logf(uu.x + 1e-10f) + 1e-10f);
          const float g1 = -logf(-logf(uu.y + 1e-10f) + 1e-10f);
          e = ((c0 + (double)g0) >= (c1 + (double)g1)) ? 1.0f : 0.0f;
        }
        tile[il][jl] = e;
      }
    }
    __syncthreads();
    #pragma unroll
    for (int s = 0; s < 4; ++s) {
      const int rl = s * 16 + row_base;
      f32x4 v;
      #pragma unroll
      for (int q = 0; q < 4; ++q) {
        const int jl = lane_col + q;
        v[q] = (jl > rl) ? tile[rl][jl] : ((jl < rl) ? tile[jl][rl] : 0.0f);
      }
      __builtin_nontemporal_store(v,
          reinterpret_cast<f32x4*>(ob + (size_t)(ti * TILE + rl) * NN
                                      + ti * TILE + lane_col));
    }
  }
}

extern "C" void kernel_launch(void* const* d_in, const int* in_sizes, int n_in,
                              void* d_out, int out_size, void* d_ws, size_t ws_size,
                              hipStream_t stream) {
  const float* x        = (const float*)d_in[0];
  const float* stats    = (const float*)d_in[1];
  const float* u        = (const float*)d_in[2];
  const float* ln0_g    = (const float*)d_in[3];
  const float* ln0_b    = (const float*)d_in[4];
  const float* rb1_ln_g = (const float*)d_in[5];
  const float* rb1_ln_b = (const float*)d_in[6];
  const float* rb1_w1   = (const float*)d_in[7];
  const float* rb1_b1   = (const float*)d_in[8];
  const float* rb1_w2   = (const float*)d_in[9];
  const float* rb1_b2   = (const float*)d_in[10];
  const float* rb1_wp   = (const float*)d_in[11];
  const float* rb1_bp   = (const float*)d_in[12];
  const float* rb2_ln_g = (const float*)d_in[13];
  const float* rb2_ln_b = (const float*)d_in[14];
  const float* rb2_w1   = (const float*)d_in[15];
  const float* rb2_b1   = (const float*)d_in[16];
  const float* rb2_w2   = (const float*)d_in[17];
  const float* rb2_b2   = (const float*)d_in[18];
  const float* att_ln_g = (const float*)d_in[19];
  const float* att_ln_b = (const float*)d_in[20];
  const float* att_win  = (const float*)d_in[21];
  const float* att_bin  = (const float*)d_in[22];
  const float* att_wout = (const float*)d_in[23];
  const float* att_bout = (const float*)d_in[24];
  const float* out_w    = (const float*)d_in[25];
  const float* out_b    = (const float*)d_in[26];
  const float* fin_w    = (const float*)d_in[27];
  const float* fin_b    = (const float*)d_in[28];
  // d_in[29] = temp: tau = |temp| > 0 is argmax-invariant -> unused.

  float* out   = (float*)d_out;            // [16, 1024, 1024] = 64MB
  double* c_ws = (double*)d_ws;            // 32 doubles (256B — safe)

  // G/H/T scratch in the TAIL of d_out (3 x 16 x 256 doubles = 96KB).
  // Consumed entirely before adj_tile_kernel overwrites all of d_out.
  double* G = (double*)(out + ((size_t)16 * NN * NN - 3 * 16 * HD * 2));
  double* H = G + 16 * HD;
  double* T = H + 16 * HD;

  const float* att_win_v = att_win + 2 * HD * HD;  // v-slice of in_proj
  const float* att_bin_v = att_bin + 2 * HD;

  void* kargs[] = {
    (void*)&x, (void*)&stats, (void*)&ln0_g, (void*)&ln0_b,
    (void*)&rb1_ln_g, (void*)&rb1_ln_b, (void*)&rb1_w1, (void*)&rb1_b1,
    (void*)&rb1_w2, (void*)&rb1_b2, (void*)&rb1_wp, (void*)&rb1_bp,
    (void*)&rb2_ln_g, (void*)&rb2_ln_b, (void*)&rb2_w1, (void*)&rb2_b1,
    (void*)&rb2_w2, (void*)&rb2_b2, (void*)&att_ln_g, (void*)&att_ln_b,
    (void*)&att_win_v, (void*)&att_bin_v, (void*)&att_wout, (void*)&att_bout,
    (void*)&out_w, (void*)&out_b, (void*)&fin_w, (void*)&fin_b,
    (void*)&G, (void*)&H, (void*)&T, (void*)&c_ws
  };
  hipError_t cerr = hipLaunchCooperativeKernel(
      reinterpret_cast<void*>(head_coop), dim3(64), dim3(256), kargs, 0, stream);

  if (cerr != hipSuccess) {
    // Fallback: R7-proven 8-launch stage pipeline (identical math).
    const dim3 g64(64), t256(256);
    hipLaunchKernelGGL(k1_ln_w1, g64, t256, 0, stream,
                       x, stats, ln0_g, ln0_b, rb1_ln_g, rb1_ln_b,
                       rb1_w1, rb1_b1, G);
    hipLaunchKernelGGL(k2_w2_wp, g64, t256, 0, stream,
                       x, stats, ln0_g, ln0_b, rb1_w2, rb1_b2, rb1_wp, rb1_bp,
                       G, H);
    hipLaunchKernelGGL(k3_ln_mv, g64, t256, 0, stream,
                       H, rb2_ln_g, rb2_ln_b, rb2_w1, rb2_b1, G, 1);
    hipLaunchKernelGGL(k4_mv_res, g64, t256, 0, stream,
                       G, rb2_w2, rb2_b2, H);
    hipLaunchKernelGGL(k3_ln_mv, g64, t256, 0, stream,
                       H, att_ln_g, att_ln_b, att_win_v, att_bin_v, G, 0);
    hipLaunchKernelGGL(k5_mv, g64, t256, 0, stream, G, att_wout, att_bout, T);
    hipLaunchKernelGGL(k5_mv, g64, t256, 0, stream, T, out_w, out_b, G);
    hipLaunchKernelGGL(k6_fin, dim3(16), t256, 0, stream, G, fin_w, fin_b, c_ws);
  }

  hipLaunchKernelGGL(adj_tile_kernel, dim3(NT * (NT + 1) / 2, 16), dim3(256),
                     0, stream, u, c_ws, out);
}